// Round 8
// baseline (158.934 us; speedup 1.0000x reference)
//
#include <hip/hip_runtime.h>
#include <math.h>

// Problem constants
#define NPRED 1024
#define NT 64
#define PD 85            // 5 + 80 classes
#define NLOGIT 79        // pred[:, 6:] -> 85-6 columns (reference quirk)
#define QBLK 8           // blocks per sample
#define RPB 128          // pred rows per block
#define THREADS 256      // 2 lanes per row
#define SLAB_DW (RPB * PD)               // 10880 dwords = 43520 B
#define SLAB_F4 (SLAB_DW / 4)            // 2720 float4
#define ITERS ((SLAB_F4 + THREADS - 1) / THREADS)   // 11

__device__ __forceinline__ float softplusf(float x) {
    return fmaxf(x, 0.0f) + log1pf(expf(-fabsf(x)));
}

// part[] planes (each of size nblk):
//  0 sp | 1 cntA 2 bboxA 3 ceA 4 sfmA 5 spmA | 6 cntB 7 bboxB 8 ceB 9 sfmB 10 spmB
// 11 block_max | 12 kv

__global__ __launch_bounds__(THREADS)
void detloss_fused(const float* __restrict__ preds,
                   const float* __restrict__ targets,
                   float* __restrict__ part,
                   float* __restrict__ ps,
                   int*   __restrict__ cnt,
                   float* __restrict__ out,
                   int nb, int nblk)
{
    const int bx   = blockIdx.x;
    const int b    = bx >> 3;
    const int q    = bx & 7;
    const int tid  = threadIdx.x;
    const int row  = tid >> 1;          // 0..127
    const int half = tid & 1;           // 32-target half

    __shared__ float  slab[SLAB_DW];    // raw pred rows (43520 B)
    __shared__ float  tgs[NT * 5];
    __shared__ float4 tb[NT];
    __shared__ float  tcl[NT];
    __shared__ unsigned long long vmask_s;
    __shared__ float  red[4][11];
    __shared__ float  redm[4];
    __shared__ float  bmax_s;
    __shared__ int    ticket_s;

    // ---- coalesced stream: slab -> LDS raw (no extraction arithmetic) ----
    const float4* g4 = (const float4*)(preds + ((size_t)b * NPRED + (size_t)q * RPB) * PD);
    float4 tmp[ITERS];
    #pragma unroll
    for (int i = 0; i < ITERS; ++i) {
        const int idx = tid + i * THREADS;
        if (idx < SLAB_F4) tmp[i] = g4[idx];
    }
    float4 tg4;
    if (tid < (NT * 5 / 4)) tg4 = ((const float4*)(targets + (size_t)b * NT * 5))[tid];

    float4* s4 = (float4*)slab;
    #pragma unroll
    for (int i = 0; i < ITERS; ++i) {
        const int idx = tid + i * THREADS;
        if (idx < SLAB_F4) s4[idx] = tmp[i];
    }
    if (tid < (NT * 5 / 4)) ((float4*)tgs)[tid] = tg4;
    __syncthreads();

    if (tid < NT) {   // exactly wave 0
        float a = tgs[tid*5], c = tgs[tid*5+1], d = tgs[tid*5+2], e = tgs[tid*5+3], f = tgs[tid*5+4];
        tb[tid]  = make_float4(a, c, d, e);
        tcl[tid] = f;
        unsigned long long bl = __ballot(f >= 0.0f);
        if (tid == 0) vmask_s = bl;
    }
    __syncthreads();

    const unsigned long long vmask = vmask_s;
    const float px1 = slab[row*PD+0], py1 = slab[row*PD+1];
    const float px2 = slab[row*PD+2], py2 = slab[row*PD+3];
    const float conf = slab[row*PD+4];

    // ---- half-scan over targets [half*32, half*32+32) ----
    const float parea = (px2 - px1) * (py2 - py1);
    const int t0 = half * 32;
    float best = -INFINITY;
    int   bidx = t0;
    #pragma unroll 8
    for (int i = 0; i < 32; ++i) {
        const int t = t0 + i;
        const float4 tt = tb[t];
        float w = fminf(px2, tt.z) - fmaxf(px1, tt.x); w = fmaxf(w, 0.0f);
        float h = fminf(py2, tt.w) - fmaxf(py1, tt.y); h = fmaxf(h, 0.0f);
        float inter = w * h;
        float ta    = (tt.z - tt.x) * (tt.w - tt.y);
        float uni   = parea + ta - inter;
        float iou   = ((vmask >> t) & 1ULL) ? inter / (uni + 1e-6f) : -1.0f;
        if (iou > best) { best = iou; bidx = t; }   // strict > => first occurrence (JAX argmax)
    }

    // ---- combine the two halves (tie -> lower-index half) ----
    const float obest = __shfl_xor(best, 1);
    const int   obidx = __shfl_xor(bidx, 1);
    const float bA = half ? obest : best;
    const int   iA = half ? obidx : bidx;
    const float bB = half ? best  : obest;
    const int   iB = half ? bidx  : obidx;
    const float fbest = (bA >= bB) ? bA : bB;
    const int   fidx  = (bA >= bB) ? iA : iB;

    // ---- block max ----
    {
        float v = fbest;
        #pragma unroll
        for (int o = 32; o > 0; o >>= 1) v = fmaxf(v, __shfl_down(v, o));
        if ((tid & 63) == 0) redm[tid >> 6] = v;
        __syncthreads();
        if (tid == 0) bmax_s = fmaxf(fmaxf(redm[0], redm[1]), fmaxf(redm[2], redm[3]));
        __syncthreads();
    }
    const float bmax = bmax_s;
    const bool cA = (fbest > 0.5f);
    const bool cB = (fbest == bmax);

    const float sp = softplusf(conf);
    float vals[11];
    #pragma unroll
    for (int j = 0; j < 11; ++j) vals[j] = 0.0f;
    if (half == 0) vals[0] = sp;

    if (cA || cB) {
        // logits from the LDS slab (already staged)
        const float* lg = &slab[row * PD + 6];
        const int base = half * 40;
        const int len  = half ? 39 : 40;
        float m = -INFINITY, s = 0.0f;
        #pragma unroll 8
        for (int i = 0; i < len; ++i) {
            float v  = lg[base + i];
            float nm = fmaxf(m, v);
            s = s * expf(m - nm) + expf(v - nm);
            m = nm;
        }
        const float om = __shfl_xor(m, 1);
        const float os = __shfl_xor(s, 1);
        const float nm = fmaxf(m, om);
        const float st = s * expf(m - nm) + os * expf(om - nm);
        const float lse = nm + logf(st);

        if (half == 0) {
            const float4 mt = tb[fidx];
            float dd[4] = { px1 - mt.x, py1 - mt.y, px2 - mt.z, py2 - mt.w };
            float bb = 0.0f;
            #pragma unroll
            for (int i = 0; i < 4; ++i) {
                float ad = fabsf(dd[i]);
                bb += (ad < 1.0f) ? 0.5f * dd[i] * dd[i] : ad - 0.5f;
            }
            int label = (int)tcl[fidx];
            label = label < 0 ? 0 : (label > NLOGIT - 1 ? NLOGIT - 1 : label);
            const float cev = lse - lg[label];
            const float sfm = softplusf(-conf);

            if (cA) { vals[1] += 1.0f; vals[2] += bb; vals[3] += cev; vals[4] += sfm; vals[5] += sp; }
            if (cB) { vals[6] += 1.0f; vals[7] += bb; vals[8] += cev; vals[9] += sfm; vals[10] += sp; }
        }
    }

    // ---- block sums ----
    #pragma unroll
    for (int j = 0; j < 11; ++j) {
        float v = vals[j];
        #pragma unroll
        for (int o = 32; o > 0; o >>= 1) v += __shfl_down(v, o);
        if ((tid & 63) == 0) red[tid >> 6][j] = v;
    }
    __syncthreads();
    if (tid < 11)  part[(size_t)tid * nblk + bx] = red[0][tid] + red[1][tid] + red[2][tid] + red[3][tid];
    if (tid == 11) part[(size_t)11  * nblk + bx] = bmax;
    if (tid == 12) part[(size_t)12  * nblk + bx] = (float)__popcll(vmask);

    // ---- last-block-per-sample finalize (device-scope ticket) ----
    __threadfence();            // release this block's part[] writes
    __syncthreads();
    if (tid == 0) ticket_s = atomicAdd(&cnt[b], 1);
    __syncthreads();

    if (ticket_s == QBLK - 1 && tid == 0) {
        __threadfence();        // acquire other blocks' part[] writes
        const int base = b * QBLK;
        float bm[QBLK];
        #pragma unroll
        for (int i = 0; i < QBLK; ++i) bm[i] = part[(size_t)11 * nblk + base + i];
        float gmax = bm[0];
        #pragma unroll
        for (int i = 1; i < QBLK; ++i) gmax = fmaxf(gmax, bm[i]);

        float tot[11];
        #pragma unroll
        for (int j = 0; j < 11; ++j) tot[j] = 0.0f;
        #pragma unroll
        for (int i = 0; i < QBLK; ++i) {
            const int idx = base + i;
            #pragma unroll
            for (int j = 0; j < 6; ++j) tot[j] += part[(size_t)j * nblk + idx];
            const float mB = (bm[i] == gmax) ? 1.0f : 0.0f;
            #pragma unroll
            for (int j = 6; j < 11; ++j) tot[j] += mB * part[(size_t)j * nblk + idx];
        }
        const int kv = (int)part[(size_t)12 * nblk + base];

        const float sp_total = tot[0];
        const bool  anym = (tot[1] > 0.0f);
        const float mcnt = anym ? tot[1] : tot[6];
        const float bboxs= anym ? tot[2] : tot[7];
        const float ces  = anym ? tot[3] : tot[8];
        const float sfms = anym ? tot[4] : tot[9];
        const float spms = anym ? tot[5] : tot[10];
        const float ucnt = (float)NPRED - mcnt;
        const float sfus = sp_total - spms;
        const float bbox_loss = bboxs / fmaxf(mcnt * 4.0f, 1.0f);
        const float cls_loss  = ces   / fmaxf(mcnt, 1.0f);
        const float conf_m    = sfms  / fmaxf(mcnt, 1.0f);
        const float conf_u    = sfus  / fmaxf(ucnt, 1.0f);
        const float conf_loss = (ucnt > 0.0f) ? (conf_m + conf_u) * 0.5f : conf_m;
        const float loss_valid   = bbox_loss + cls_loss + conf_loss;
        const float loss_novalid = sp_total / (float)NPRED;
        ps[b] = (kv > 0) ? loss_valid : loss_novalid;

        __threadfence();        // release ps[b]
        const int t2 = atomicAdd(&cnt[nb], 1);
        if (t2 == nb - 1) {     // all samples done
            __threadfence();    // acquire all ps[]
            float ssum = 0.0f;
            for (int i = 0; i < nb; ++i) ssum += ps[i];   // fixed order -> deterministic
            out[0] = ssum / (float)nb;
        }
    }
}

extern "C" void kernel_launch(void* const* d_in, const int* in_sizes, int n_in,
                              void* d_out, int out_size, void* d_ws, size_t ws_size,
                              hipStream_t stream) {
    const float* preds   = (const float*)d_in[0];
    const float* targets = (const float*)d_in[1];
    float* out = (float*)d_out;

    const int nb   = in_sizes[0] / (NPRED * PD);   // B = 128
    const int nblk = nb * QBLK;                    // 1024

    float* part = (float*)d_ws;                    // 13 * nblk floats
    float* ps   = part + (size_t)13 * nblk;        // nb floats
    int*   cnt  = (int*)(ps + nb);                 // nb + 1 ints

    hipMemsetAsync(cnt, 0, (size_t)(nb + 1) * sizeof(int), stream);
    hipLaunchKernelGGL(detloss_fused, dim3(nblk), dim3(THREADS), 0, stream,
                       preds, targets, part, ps, cnt, out, nb, nblk);
}

// Round 9
// 132.938 us; speedup vs baseline: 1.1956x; 1.1956x over previous
//
#include <hip/hip_runtime.h>
#include <math.h>

// Problem constants
#define NPRED 1024
#define NT 64
#define PD 85            // 5 + 80 classes
#define NLOGIT 79        // pred[:, 6:] -> 85-6 columns (reference quirk)
#define QBLK 8           // blocks per sample
#define RPB 128          // pred rows per block
#define THREADS 256      // 2 lanes per row
#define SLAB_DW (RPB * PD)               // 10880 dwords = 43520 B
#define SLAB_F4 (SLAB_DW / 4)            // 2720 float4
#define FULL_F4 (10 * THREADS)           // 2560 handled in 5 pair-rounds
#define TAIL_F4 (SLAB_F4 - FULL_F4)      // 160

__device__ __forceinline__ float softplusf(float x) {
    return fmaxf(x, 0.0f) + log1pf(expf(-fabsf(x)));
}

// part[] planes (each of size nblk):
//  0 sp | 1 cntA 2 bboxA 3 ceA 4 sfmA 5 spmA | 6 cntB 7 bboxB 8 ceB 9 sfmB 10 spmB
// 11 block_max | 12 kv

__global__ __launch_bounds__(THREADS)
void detloss_fused(const float* __restrict__ preds,
                   const float* __restrict__ targets,
                   float* __restrict__ part,
                   float* __restrict__ ps,
                   int*   __restrict__ cnt,
                   float* __restrict__ out,
                   int nb, int nblk)
{
    const int bx   = blockIdx.x;
    const int b    = bx >> 3;
    const int q    = bx & 7;
    const int tid  = threadIdx.x;
    const int row  = tid >> 1;          // 0..127
    const int half = tid & 1;           // 32-target half

    __shared__ float  slab[SLAB_DW];    // raw pred rows (43520 B)
    __shared__ float  tgs[NT * 5];
    __shared__ float4 tb[NT];
    __shared__ float  tcl[NT];
    __shared__ unsigned long long vmask_s;
    __shared__ float  red[4][11];
    __shared__ float  redm[4];
    __shared__ float  bmax_s;
    __shared__ int    ticket_s;
    __shared__ int    t2_s;
    __shared__ float  r2[2];

    // ---- targets load issued first (tiny) ----
    float4 tg4;
    if (tid < (NT * 5 / 4)) tg4 = ((const float4*)(targets + (size_t)b * NT * 5))[tid];

    // ---- coalesced slab stream -> LDS; named regs only (NO arrays -> no scratch) ----
    const float4* g4 = (const float4*)(preds + ((size_t)b * NPRED + (size_t)q * RPB) * PD);
    float4* s4 = (float4*)slab;
    #pragma unroll 1
    for (int i = 0; i < 5; ++i) {
        const int i0 = tid + (2 * i) * THREADS;
        const int i1 = tid + (2 * i + 1) * THREADS;
        const float4 va = g4[i0];
        const float4 vb = g4[i1];
        s4[i0] = va;
        s4[i1] = vb;
    }
    if (tid < TAIL_F4) s4[FULL_F4 + tid] = g4[FULL_F4 + tid];
    if (tid < (NT * 5 / 4)) ((float4*)tgs)[tid] = tg4;
    __syncthreads();

    if (tid < NT) {   // exactly wave 0
        float a = tgs[tid*5], c = tgs[tid*5+1], d = tgs[tid*5+2], e = tgs[tid*5+3], f = tgs[tid*5+4];
        tb[tid]  = make_float4(a, c, d, e);
        tcl[tid] = f;
        unsigned long long bl = __ballot(f >= 0.0f);
        if (tid == 0) vmask_s = bl;
    }
    __syncthreads();

    const unsigned long long vmask = vmask_s;
    const float px1 = slab[row*PD+0], py1 = slab[row*PD+1];
    const float px2 = slab[row*PD+2], py2 = slab[row*PD+3];
    const float conf = slab[row*PD+4];

    // ---- half-scan over targets [half*32, half*32+32) ----
    const float parea = (px2 - px1) * (py2 - py1);
    const int t0 = half * 32;
    float best = -INFINITY;
    int   bidx = t0;
    #pragma unroll 8
    for (int i = 0; i < 32; ++i) {
        const int t = t0 + i;
        const float4 tt = tb[t];
        float w = fminf(px2, tt.z) - fmaxf(px1, tt.x); w = fmaxf(w, 0.0f);
        float h = fminf(py2, tt.w) - fmaxf(py1, tt.y); h = fmaxf(h, 0.0f);
        float inter = w * h;
        float ta    = (tt.z - tt.x) * (tt.w - tt.y);
        float uni   = parea + ta - inter;
        float iou   = ((vmask >> t) & 1ULL) ? inter / (uni + 1e-6f) : -1.0f;
        if (iou > best) { best = iou; bidx = t; }   // strict > => first occurrence (JAX argmax)
    }

    // ---- combine the two halves (tie -> lower-index half) ----
    const float obest = __shfl_xor(best, 1);
    const int   obidx = __shfl_xor(bidx, 1);
    const float bA = half ? obest : best;
    const int   iA = half ? obidx : bidx;
    const float bB = half ? best  : obest;
    const int   iB = half ? bidx  : obidx;
    const float fbest = (bA >= bB) ? bA : bB;
    const int   fidx  = (bA >= bB) ? iA : iB;

    // ---- block max ----
    {
        float v = fbest;
        #pragma unroll
        for (int o = 32; o > 0; o >>= 1) v = fmaxf(v, __shfl_down(v, o));
        if ((tid & 63) == 0) redm[tid >> 6] = v;
        __syncthreads();
        if (tid == 0) bmax_s = fmaxf(fmaxf(redm[0], redm[1]), fmaxf(redm[2], redm[3]));
        __syncthreads();
    }
    const float bmax = bmax_s;
    const bool cA = (fbest > 0.5f);
    const bool cB = (fbest == bmax);

    const float sp = softplusf(conf);
    float vals[11];
    #pragma unroll
    for (int j = 0; j < 11; ++j) vals[j] = 0.0f;
    if (half == 0) vals[0] = sp;

    if (cA || cB) {
        // logits from the LDS slab (already staged)
        const float* lg = &slab[row * PD + 6];
        const int base = half * 40;
        const int len  = half ? 39 : 40;
        float m = -INFINITY, s = 0.0f;
        #pragma unroll 8
        for (int i = 0; i < len; ++i) {
            float v  = lg[base + i];
            float nm = fmaxf(m, v);
            s = s * expf(m - nm) + expf(v - nm);
            m = nm;
        }
        const float om = __shfl_xor(m, 1);
        const float os = __shfl_xor(s, 1);
        const float nm = fmaxf(m, om);
        const float st = s * expf(m - nm) + os * expf(om - nm);
        const float lse = nm + logf(st);

        if (half == 0) {
            const float4 mt = tb[fidx];
            float dd[4] = { px1 - mt.x, py1 - mt.y, px2 - mt.z, py2 - mt.w };
            float bb = 0.0f;
            #pragma unroll
            for (int i = 0; i < 4; ++i) {
                float ad = fabsf(dd[i]);
                bb += (ad < 1.0f) ? 0.5f * dd[i] * dd[i] : ad - 0.5f;
            }
            int label = (int)tcl[fidx];
            label = label < 0 ? 0 : (label > NLOGIT - 1 ? NLOGIT - 1 : label);
            const float cev = lse - lg[label];
            const float sfm = softplusf(-conf);

            if (cA) { vals[1] += 1.0f; vals[2] += bb; vals[3] += cev; vals[4] += sfm; vals[5] += sp; }
            if (cB) { vals[6] += 1.0f; vals[7] += bb; vals[8] += cev; vals[9] += sfm; vals[10] += sp; }
        }
    }

    // ---- block sums ----
    #pragma unroll
    for (int j = 0; j < 11; ++j) {
        float v = vals[j];
        #pragma unroll
        for (int o = 32; o > 0; o >>= 1) v += __shfl_down(v, o);
        if ((tid & 63) == 0) red[tid >> 6][j] = v;
    }
    __syncthreads();
    if (tid < 11)  part[(size_t)tid * nblk + bx] = red[0][tid] + red[1][tid] + red[2][tid] + red[3][tid];
    if (tid == 11) part[(size_t)11  * nblk + bx] = bmax;
    if (tid == 12) part[(size_t)12  * nblk + bx] = (float)__popcll(vmask);

    // ---- last-block-per-sample finalize (device-scope ticket) ----
    __threadfence();            // release this block's part[] writes
    __syncthreads();
    if (tid == 0) ticket_s = atomicAdd(&cnt[b], 1);
    __syncthreads();

    if (ticket_s == QBLK - 1) {
        if (tid == 0) {
            __threadfence();        // acquire other blocks' part[] writes
            const int base = b * QBLK;
            float bm[QBLK];
            #pragma unroll
            for (int i = 0; i < QBLK; ++i) bm[i] = part[(size_t)11 * nblk + base + i];
            float gmax = bm[0];
            #pragma unroll
            for (int i = 1; i < QBLK; ++i) gmax = fmaxf(gmax, bm[i]);

            float tot[11];
            #pragma unroll
            for (int j = 0; j < 11; ++j) tot[j] = 0.0f;
            #pragma unroll
            for (int i = 0; i < QBLK; ++i) {
                const int idx = base + i;
                #pragma unroll
                for (int j = 0; j < 6; ++j) tot[j] += part[(size_t)j * nblk + idx];
                const float mB = (bm[i] == gmax) ? 1.0f : 0.0f;
                #pragma unroll
                for (int j = 6; j < 11; ++j) tot[j] += mB * part[(size_t)j * nblk + idx];
            }
            const int kv = (int)part[(size_t)12 * nblk + base];

            const float sp_total = tot[0];
            const bool  anym = (tot[1] > 0.0f);
            const float mcnt = anym ? tot[1] : tot[6];
            const float bboxs= anym ? tot[2] : tot[7];
            const float ces  = anym ? tot[3] : tot[8];
            const float sfms = anym ? tot[4] : tot[9];
            const float spms = anym ? tot[5] : tot[10];
            const float ucnt = (float)NPRED - mcnt;
            const float sfus = sp_total - spms;
            const float bbox_loss = bboxs / fmaxf(mcnt * 4.0f, 1.0f);
            const float cls_loss  = ces   / fmaxf(mcnt, 1.0f);
            const float conf_m    = sfms  / fmaxf(mcnt, 1.0f);
            const float conf_u    = sfus  / fmaxf(ucnt, 1.0f);
            const float conf_loss = (ucnt > 0.0f) ? (conf_m + conf_u) * 0.5f : conf_m;
            const float loss_valid   = bbox_loss + cls_loss + conf_loss;
            const float loss_novalid = sp_total / (float)NPRED;
            ps[b] = (kv > 0) ? loss_valid : loss_novalid;

            __threadfence();    // release ps[b]
            t2_s = atomicAdd(&cnt[nb], 1);
        }
        __syncthreads();

        if (t2_s == nb - 1) {   // last sample finished: block-parallel mean
            __threadfence();    // acquire all ps[]
            if (tid < 128) {    // waves 0-1 fully active (wave-uniform branch)
                float x = (tid < nb) ? ps[tid] : 0.0f;
                #pragma unroll
                for (int o = 32; o > 0; o >>= 1) x += __shfl_down(x, o);
                if ((tid & 63) == 0) r2[tid >> 6] = x;
            }
            __syncthreads();
            if (tid == 0) out[0] = (r2[0] + r2[1]) / (float)nb;
        }
    }
}

extern "C" void kernel_launch(void* const* d_in, const int* in_sizes, int n_in,
                              void* d_out, int out_size, void* d_ws, size_t ws_size,
                              hipStream_t stream) {
    const float* preds   = (const float*)d_in[0];
    const float* targets = (const float*)d_in[1];
    float* out = (float*)d_out;

    const int nb   = in_sizes[0] / (NPRED * PD);   // B = 128
    const int nblk = nb * QBLK;                    // 1024

    float* part = (float*)d_ws;                    // 13 * nblk floats
    float* ps   = part + (size_t)13 * nblk;        // nb floats
    int*   cnt  = (int*)(ps + nb);                 // nb + 1 ints

    hipMemsetAsync(cnt, 0, (size_t)(nb + 1) * sizeof(int), stream);
    hipLaunchKernelGGL(detloss_fused, dim3(nblk), dim3(THREADS), 0, stream,
                       preds, targets, part, ps, cnt, out, nb, nblk);
}

// Round 10
// 37.301 us; speedup vs baseline: 4.2609x; 3.5639x over previous
//
#include <hip/hip_runtime.h>
#include <math.h>

// Problem constants
#define NPRED 1024
#define NT 64
#define PD 85            // 5 + 80 classes
#define NLOGIT 79        // pred[:, 6:] -> 85-6 columns (reference quirk)
#define QBLK 8           // k1 blocks per sample
#define RPB 128          // pred rows per block
#define THREADS 256      // 2 lanes per row
#define SLAB_DW (RPB * PD)               // 10880 dwords = 43520 B
#define SLAB_F4 (SLAB_DW / 4)            // 2720 float4
#define FULL_IT 10                       // 10 * 256 = 2560 f4
#define TAIL_BASE (SLAB_F4 - THREADS)    // 2464: tail covers [2464, 2720)

__device__ __forceinline__ float softplusf(float x) {
    return fmaxf(x, 0.0f) + log1pf(expf(-fabsf(x)));
}

// direct global->LDS DMA, 16B per lane, no VGPR round-trip
__device__ __forceinline__ void load_lds16(const float4* g, float4* l) {
    __builtin_amdgcn_global_load_lds((const __attribute__((address_space(1))) void*)g,
                                     (__attribute__((address_space(3))) void*)l,
                                     16, 0, 0);
}

// part[] planes (each of size nblk):
//  0 sp | 1 cntA 2 bboxA 3 ceA 4 sfmA 5 spmA | 6 cntB 7 bboxB 8 ceB 9 sfmB 10 spmB
// 11 block_max | 12 kv

__global__ __launch_bounds__(THREADS)
void k1_match(const float* __restrict__ preds,
              const float* __restrict__ targets,
              float* __restrict__ part, int nblk)
{
    const int bx   = blockIdx.x;
    const int b    = bx >> 3;
    const int q    = bx & 7;
    const int tid  = threadIdx.x;
    const int row  = tid >> 1;          // 0..127
    const int half = tid & 1;           // 32-target half
    const int wbase = tid & 192;        // wave-uniform lane-0 index (tid>>6)*64

    __shared__ float  slab[SLAB_DW];    // raw pred rows (43520 B)
    __shared__ float  tgs[NT * 5];
    __shared__ float4 tb[NT];
    __shared__ float  tcl[NT];
    __shared__ unsigned long long vmask_s;
    __shared__ float  red[4][11];
    __shared__ float  redm[4];
    __shared__ float  bmax_s;

    // ---- stage pred slab via global_load_lds (all 11 DMAs in flight) ----
    const float4* g4 = (const float4*)(preds + ((size_t)b * NPRED + (size_t)q * RPB) * PD);
    float4* s4 = (float4*)slab;
    #pragma unroll
    for (int i = 0; i < FULL_IT; ++i) {
        load_lds16(g4 + i * THREADS + tid, s4 + i * THREADS + wbase);
    }
    load_lds16(g4 + TAIL_BASE + tid, s4 + TAIL_BASE + wbase);   // overlap-tail, benign double-write

    // ---- targets (tiny, via regs) ----
    float4 tg4;
    if (tid < (NT * 5 / 4)) tg4 = ((const float4*)(targets + (size_t)b * NT * 5))[tid];
    if (tid < (NT * 5 / 4)) ((float4*)tgs)[tid] = tg4;
    __syncthreads();    // drains vmcnt (global_load_lds) + lgkmcnt

    if (tid < NT) {   // exactly wave 0
        float a = tgs[tid*5], c = tgs[tid*5+1], d = tgs[tid*5+2], e = tgs[tid*5+3], f = tgs[tid*5+4];
        tb[tid]  = make_float4(a, c, d, e);
        tcl[tid] = f;
        unsigned long long bl = __ballot(f >= 0.0f);
        if (tid == 0) vmask_s = bl;
    }
    __syncthreads();

    const unsigned long long vmask = vmask_s;
    const float px1 = slab[row*PD+0], py1 = slab[row*PD+1];
    const float px2 = slab[row*PD+2], py2 = slab[row*PD+3];
    const float conf = slab[row*PD+4];

    // ---- half-scan over targets [half*32, half*32+32) ----
    const float parea = (px2 - px1) * (py2 - py1);
    const int t0 = half * 32;
    float best = -INFINITY;
    int   bidx = t0;
    #pragma unroll 8
    for (int i = 0; i < 32; ++i) {
        const int t = t0 + i;
        const float4 tt = tb[t];
        float w = fminf(px2, tt.z) - fmaxf(px1, tt.x); w = fmaxf(w, 0.0f);
        float h = fminf(py2, tt.w) - fmaxf(py1, tt.y); h = fmaxf(h, 0.0f);
        float inter = w * h;
        float ta    = (tt.z - tt.x) * (tt.w - tt.y);
        float uni   = parea + ta - inter;
        float iou   = ((vmask >> t) & 1ULL) ? inter / (uni + 1e-6f) : -1.0f;
        if (iou > best) { best = iou; bidx = t; }   // strict > => first occurrence (JAX argmax)
    }

    // ---- combine the two halves (tie -> lower-index half) ----
    const float obest = __shfl_xor(best, 1);
    const int   obidx = __shfl_xor(bidx, 1);
    const float bA = half ? obest : best;
    const int   iA = half ? obidx : bidx;
    const float bB = half ? best  : obest;
    const int   iB = half ? bidx  : obidx;
    const float fbest = (bA >= bB) ? bA : bB;
    const int   fidx  = (bA >= bB) ? iA : iB;

    // ---- block max ----
    {
        float v = fbest;
        #pragma unroll
        for (int o = 32; o > 0; o >>= 1) v = fmaxf(v, __shfl_down(v, o));
        if ((tid & 63) == 0) redm[tid >> 6] = v;
        __syncthreads();
        if (tid == 0) bmax_s = fmaxf(fmaxf(redm[0], redm[1]), fmaxf(redm[2], redm[3]));
        __syncthreads();
    }
    const float bmax = bmax_s;
    const bool cA = (fbest > 0.5f);
    const bool cB = (fbest == bmax);

    const float sp = softplusf(conf);
    float vals[11];
    #pragma unroll
    for (int j = 0; j < 11; ++j) vals[j] = 0.0f;
    if (half == 0) vals[0] = sp;

    if (cA || cB) {
        // logits from the LDS slab (already staged)
        const float* lg = &slab[row * PD + 6];
        const int base = half * 40;
        const int len  = half ? 39 : 40;
        float m = -INFINITY, s = 0.0f;
        #pragma unroll 8
        for (int i = 0; i < len; ++i) {
            float v  = lg[base + i];
            float nm = fmaxf(m, v);
            s = s * expf(m - nm) + expf(v - nm);
            m = nm;
        }
        const float om = __shfl_xor(m, 1);
        const float os = __shfl_xor(s, 1);
        const float nm = fmaxf(m, om);
        const float st = s * expf(m - nm) + os * expf(om - nm);
        const float lse = nm + logf(st);

        if (half == 0) {
            const float4 mt = tb[fidx];
            float dd[4] = { px1 - mt.x, py1 - mt.y, px2 - mt.z, py2 - mt.w };
            float bb = 0.0f;
            #pragma unroll
            for (int i = 0; i < 4; ++i) {
                float ad = fabsf(dd[i]);
                bb += (ad < 1.0f) ? 0.5f * dd[i] * dd[i] : ad - 0.5f;
            }
            int label = (int)tcl[fidx];
            label = label < 0 ? 0 : (label > NLOGIT - 1 ? NLOGIT - 1 : label);
            const float cev = lse - lg[label];
            const float sfm = softplusf(-conf);

            if (cA) { vals[1] += 1.0f; vals[2] += bb; vals[3] += cev; vals[4] += sfm; vals[5] += sp; }
            if (cB) { vals[6] += 1.0f; vals[7] += bb; vals[8] += cev; vals[9] += sfm; vals[10] += sp; }
        }
    }

    // ---- block sums ----
    #pragma unroll
    for (int j = 0; j < 11; ++j) {
        float v = vals[j];
        #pragma unroll
        for (int o = 32; o > 0; o >>= 1) v += __shfl_down(v, o);
        if ((tid & 63) == 0) red[tid >> 6][j] = v;
    }
    __syncthreads();
    if (tid < 11)  part[(size_t)tid * nblk + bx] = red[0][tid] + red[1][tid] + red[2][tid] + red[3][tid];
    if (tid == 11) part[(size_t)11  * nblk + bx] = bmax;
    if (tid == 12) part[(size_t)12  * nblk + bx] = (float)__popcll(vmask);
}

// ------------------------------------------------------------------
// K2: one block of 1024 threads; 8 lanes/sample butterfly combine,
//     per-sample loss, final mean. (validated in r5/r6)
// ------------------------------------------------------------------
__global__ __launch_bounds__(1024)
void k2_final(const float* __restrict__ part, float* __restrict__ out,
              int nb, int nblk)
{
    const int t = threadIdx.x;
    const int s = t >> 3, k = t & 7;
    const int bx = s * 8 + k;

    __shared__ float ps[128];
    __shared__ float r2[2];

    float v[13];
    #pragma unroll
    for (int j = 0; j < 13; ++j) v[j] = part[(size_t)j * nblk + bx];

    float gmax = v[11];
    #pragma unroll
    for (int o = 1; o < 8; o <<= 1) gmax = fmaxf(gmax, __shfl_xor(gmax, o));
    const float mB = (v[11] == gmax) ? 1.0f : 0.0f;
    #pragma unroll
    for (int j = 6; j <= 10; ++j) v[j] *= mB;
    #pragma unroll
    for (int j = 0; j < 11; ++j) {
        #pragma unroll
        for (int o = 1; o < 8; o <<= 1) v[j] += __shfl_xor(v[j], o);
    }

    if (k == 0 && s < nb) {
        const float sp_total = v[0];
        const bool  anym = (v[1] > 0.0f);
        const float mcnt = anym ? v[1] : v[6];
        const float bboxs= anym ? v[2] : v[7];
        const float ces  = anym ? v[3] : v[8];
        const float sfms = anym ? v[4] : v[9];
        const float spms = anym ? v[5] : v[10];
        const float ucnt = (float)NPRED - mcnt;
        const float sfus = sp_total - spms;
        const float bbox_loss = bboxs / fmaxf(mcnt * 4.0f, 1.0f);
        const float cls_loss  = ces   / fmaxf(mcnt, 1.0f);
        const float conf_m    = sfms  / fmaxf(mcnt, 1.0f);
        const float conf_u    = sfus  / fmaxf(ucnt, 1.0f);
        const float conf_loss = (ucnt > 0.0f) ? (conf_m + conf_u) * 0.5f : conf_m;
        const float loss_valid   = bbox_loss + cls_loss + conf_loss;
        const float loss_novalid = sp_total / (float)NPRED;
        const int   kv = (int)v[12];
        ps[s] = (kv > 0) ? loss_valid : loss_novalid;
    }
    __syncthreads();

    if (t < 128) {
        float x = (t < nb) ? ps[t] : 0.0f;
        #pragma unroll
        for (int o = 32; o > 0; o >>= 1) x += __shfl_down(x, o);
        if ((t & 63) == 0) r2[t >> 6] = x;
    }
    __syncthreads();
    if (t == 0) out[0] = (r2[0] + r2[1]) / (float)nb;
}

extern "C" void kernel_launch(void* const* d_in, const int* in_sizes, int n_in,
                              void* d_out, int out_size, void* d_ws, size_t ws_size,
                              hipStream_t stream) {
    const float* preds   = (const float*)d_in[0];
    const float* targets = (const float*)d_in[1];
    float* out  = (float*)d_out;
    float* part = (float*)d_ws;

    const int nb   = in_sizes[0] / (NPRED * PD);   // B = 128
    const int nblk = nb * QBLK;                    // 1024

    hipLaunchKernelGGL(k1_match, dim3(nblk), dim3(THREADS), 0, stream,
                       preds, targets, part, nblk);
    hipLaunchKernelGGL(k2_final, dim3(1), dim3(1024), 0, stream,
                       part, out, nb, nblk);
}